// Round 9
// baseline (1430.742 us; speedup 1.0000x reference)
//
#include <hip/hip_runtime.h>
#include <hip/hip_bf16.h>
#include <cstddef>

#define HIDDEN 512
#define ATOM_FDIM 133
#define BOND_FDIM 14
#define FB_DIM 147
#define MAX_NB 6
#define BM 32
#define NT_MSG 16          // K-tiles message phase (512/32)
#define NT_ATOM 5          // K-tiles atom phase (160/32, pad of 133)

typedef __attribute__((ext_vector_type(8))) short s16x8;
typedef __attribute__((ext_vector_type(16))) unsigned char u8x16;
typedef __attribute__((ext_vector_type(4))) float f32x4;

__device__ __forceinline__ float uf(unsigned short u) {
    return __uint_as_float(((unsigned)u) << 16);
}
__device__ __forceinline__ unsigned short fb(float f) {
    __hip_bfloat16 h = __float2bfloat16(f);
    return *reinterpret_cast<unsigned short*>(&h);
}

// LDS A tile: 64 chunks(16B = 8 bf16 k-octet) x 32 rows, XOR-swizzled.
#define A_UNIT(ch, row) (((ch) << 5) + ((row) ^ ((ch) & 7)))

// ---------------------------------------------------------------------------
// One-time weight convert: f32 [Ksrc][512] -> bf16 MFMA-fragment order.
// ---------------------------------------------------------------------------
__global__ __launch_bounds__(256) void cvt_w(const float* __restrict__ src,
                                             unsigned short* __restrict__ dst,
                                             int Ksrc, int nchunks)
{
    int c = blockIdx.x * 256 + threadIdx.x;
    if (c >= nchunks) return;
    int tile = c >> 11, pc = c & 2047, n = pc >> 2, s = pc & 3;
    s16x8 o;
    #pragma unroll
    for (int e = 0; e < 8; e++) {
        int k = tile * 32 + s * 8 + e;
        float v = (k < Ksrc) ? src[(size_t)k * HIDDEN + n] : 0.f;
        o[e] = (short)fb(v);
    }
    reinterpret_cast<s16x8*>(dst)[c] = o;
}

// ---------------------------------------------------------------------------
// MFMA GEMM, 512 thr = 8 waves (2M x 4N), BM=32 x BN=512.  u8 messages with
// per-row scale; dequant fused into A-staging.  BM=32 halves the accumulator
// (32 AGPR) so the ENTIRE per-thread gather (6 nb x 2 chunks, 12 x 16B) is
// issued as ONE burst -> a single exposed L3 latency per block (R8 had 4).
// EPI 0: baseOut += acc (bf16 RMW); quant(relu(acc)) -> qout.
// EPI 1: quant(relu(acc + base)) -> qout.
// EPI 2: outv = bf16 relu(acc + bias).
// ---------------------------------------------------------------------------
template<int EPI, bool P0, bool P1>
__global__ __launch_bounds__(512, 4) void mfma_gemm(
    const unsigned char* __restrict__ msgq, const float* __restrict__ mscale,
    const int* __restrict__ a2a, const unsigned short* __restrict__ Wm,
    const float* __restrict__ atomf, const unsigned short* __restrict__ Wa,
    const unsigned short* __restrict__ base, const float* __restrict__ bias,
    unsigned short* __restrict__ outv, unsigned short* __restrict__ baseOut,
    unsigned char* __restrict__ qout, float* __restrict__ qscale,
    int M)
{
    __shared__ s16x8 As[64 * BM];                    // 32 KB
    __shared__ float rmax[BM][4];

    const int t    = threadIdx.x;
    const int m0   = blockIdx.x * BM;
    const int lane = t & 63;
    const int l15  = lane & 15, lhi = lane >> 4;
    const int w    = t >> 6, wm = w >> 2, wn = w & 3;
    const int rs   = t >> 4, oc16 = t & 15;          // staging: row, u8-chunk

    int srow = m0 + rs; if (srow >= M) srow = M - 1;

    f32x4 acc[8];
    #pragma unroll
    for (int nr = 0; nr < 8; nr++) acc[nr] = (f32x4){0.f, 0.f, 0.f, 0.f};

#define LOADB(B_, WT, TILE) do {                                              \
    const s16x8* bb_ = reinterpret_cast<const s16x8*>(                        \
        (WT) + (size_t)(TILE) * (HIDDEN * 32)) + ((wn * 128 + l15) * 4 + lhi);\
    _Pragma("unroll")                                                         \
    for (int nr_ = 0; nr_ < 8; nr_++) B_[nr_] = bb_[nr_ * 64];                \
} while (0)

#define TILE_MFMA(TILE, B_) do {                                              \
    s16x8 a_ = As[A_UNIT((TILE) * 4 + lhi, wm * 16 + l15)];                   \
    _Pragma("unroll")                                                         \
    for (int nr_ = 0; nr_ < 8; nr_++)                                         \
        acc[nr_] = __builtin_amdgcn_mfma_f32_16x16x32_bf16(a_, B_[nr_], acc[nr_], 0, 0, 0); \
} while (0)

#define PHASE(WT, NT) do {                                                    \
    s16x8 b_[8];                                                              \
    _Pragma("unroll 2")                                                       \
    for (int tp_ = 0; tp_ < (NT); ++tp_) {                                    \
        LOADB(b_, WT, tp_);                                                   \
        TILE_MFMA(tp_, b_);                                                   \
    }                                                                         \
} while (0)

    // ---- P0: gathered u8 message, K = 512, single-burst staged + dequant ----
    if (P0) {
        unsigned off[MAX_NB];
        float sc[MAX_NB];
        #pragma unroll
        for (int j = 0; j < MAX_NB; j++) {
            int idx = a2a[(size_t)srow * MAX_NB + j];
            off[j] = (unsigned)idx * HIDDEN + oc16 * 16;
            sc[j]  = mscale[idx];
        }
        u8x16 v0[MAX_NB], v1[MAX_NB];
        #pragma unroll
        for (int j = 0; j < MAX_NB; j++)
            v0[j] = *reinterpret_cast<const u8x16*>(msgq + off[j]);
        #pragma unroll
        for (int j = 0; j < MAX_NB; j++)
            v1[j] = *reinterpret_cast<const u8x16*>(msgq + off[j] + 256);
        __builtin_amdgcn_sched_barrier(0);   // keep the 12-load burst intact
        #pragma unroll
        for (int h = 0; h < 2; ++h) {
            float s_[16];
            #pragma unroll
            for (int e = 0; e < 16; e++) s_[e] = 0.f;
            if (h == 0) {
                #pragma unroll
                for (int j = 0; j < MAX_NB; j++)
                    #pragma unroll
                    for (int e = 0; e < 16; e++) s_[e] += sc[j] * (float)v0[j][e];
            } else {
                #pragma unroll
                for (int j = 0; j < MAX_NB; j++)
                    #pragma unroll
                    for (int e = 0; e < 16; e++) s_[e] += sc[j] * (float)v1[j][e];
            }
            s16x8 o0, o1;
            #pragma unroll
            for (int e = 0; e < 8; e++) {
                o0[e] = (short)fb(s_[e]);
                o1[e] = (short)fb(s_[e + 8]);
            }
            int ch = h * 32 + oc16 * 2;
            As[A_UNIT(ch, rs)]     = o0;
            As[A_UNIT(ch + 1, rs)] = o1;
        }
        __syncthreads();
        PHASE(Wm, NT_MSG);
    }

    // ---- P1: direct atom features, K = 160 (pad of 133) ----
    if (P1) {
        if (P0) __syncthreads();
        {
            int grow = m0 + rs;
            bool ok = grow < M;
            #pragma unroll
            for (int c8 = 0; c8 < 2; ++c8) {
                int ch = c8 * 16 + oc16;
                if (ch >= 20) break;
                s16x8 o;
                #pragma unroll
                for (int e = 0; e < 8; e++) {
                    int k = ch * 8 + e;
                    float v = (ok && k < ATOM_FDIM)
                                  ? atomf[(size_t)grow * ATOM_FDIM + k] : 0.f;
                    o[e] = (short)fb(v);
                }
                As[A_UNIT(ch, rs)] = o;
            }
        }
        __syncthreads();
        PHASE(Wa, NT_ATOM);
    }

    // ======================= epilogues =======================
    if (EPI == 2) {
        #pragma unroll
        for (int nr = 0; nr < 8; nr++) {
            int col = wn * 128 + nr * 16 + l15;
            #pragma unroll
            for (int rg = 0; rg < 4; rg++) {
                int row = m0 + wm * 16 + lhi * 4 + rg;
                if (row >= M) continue;
                outv[(size_t)row * HIDDEN + col] =
                    fb(fmaxf(acc[nr][rg] + bias[col], 0.f));
            }
        }
        return;
    }

    // EPI 0/1: fold base / relu into acc, then row-quantize to u8.
    if (EPI == 0) {
        #pragma unroll
        for (int nr = 0; nr < 8; nr++) {
            int col = wn * 128 + nr * 16 + l15;
            #pragma unroll
            for (int rg = 0; rg < 4; rg++) {
                int row = m0 + wm * 16 + lhi * 4 + rg;
                if (row < M) {
                    size_t idx = (size_t)row * HIDDEN + col;
                    baseOut[idx] = fb(acc[nr][rg] + uf(baseOut[idx]));
                }
                acc[nr][rg] = fmaxf(acc[nr][rg], 0.f);
            }
        }
    } else {
        #pragma unroll
        for (int nr = 0; nr < 8; nr++) {
            int col = wn * 128 + nr * 16 + l15;
            #pragma unroll
            for (int rg = 0; rg < 4; rg++) {
                int row = m0 + wm * 16 + lhi * 4 + rg;
                int crow = (row < M) ? row : (M - 1);
                acc[nr][rg] =
                    fmaxf(acc[nr][rg] + uf(base[(size_t)crow * HIDDEN + col]), 0.f);
            }
        }
    }

    // per-row max: 8 cols/lane -> 128 cols/wave (shfl over l15) -> LDS x4 waves
    #pragma unroll
    for (int rg = 0; rg < 4; rg++) {
        float pm = acc[0][rg];
        #pragma unroll
        for (int nr = 1; nr < 8; nr++) pm = fmaxf(pm, acc[nr][rg]);
        pm = fmaxf(pm, __shfl_xor(pm, 1));
        pm = fmaxf(pm, __shfl_xor(pm, 2));
        pm = fmaxf(pm, __shfl_xor(pm, 4));
        pm = fmaxf(pm, __shfl_xor(pm, 8));
        if (l15 == 0) rmax[wm * 16 + lhi * 4 + rg][wn] = pm;
    }
    __syncthreads();   // all MFMA reads of As done; safe to reuse As below

    unsigned char* qb = reinterpret_cast<unsigned char*>(As);
    #pragma unroll
    for (int rg = 0; rg < 4; rg++) {
        int lrow = wm * 16 + lhi * 4 + rg;
        float m4 = fmaxf(fmaxf(rmax[lrow][0], rmax[lrow][1]),
                         fmaxf(rmax[lrow][2], rmax[lrow][3]));
        float inv = (m4 > 0.f) ? 255.f / m4 : 0.f;
        #pragma unroll
        for (int nr = 0; nr < 8; nr++) {
            int col = wn * 128 + nr * 16 + l15;
            qb[lrow * HIDDEN + col] =
                (unsigned char)(acc[nr][rg] * inv + 0.5f);
        }
    }
    __syncthreads();

    {
        int grow = m0 + rs;
        if (grow < M) {
            u8x16 q0 = *reinterpret_cast<const u8x16*>(&qb[rs * HIDDEN + oc16 * 16]);
            u8x16 q1 = *reinterpret_cast<const u8x16*>(&qb[rs * HIDDEN + oc16 * 16 + 256]);
            *reinterpret_cast<u8x16*>(&qout[(size_t)grow * HIDDEN + oc16 * 16]) = q0;
            *reinterpret_cast<u8x16*>(&qout[(size_t)grow * HIDDEN + oc16 * 16 + 256]) = q1;
            if (oc16 == 0) {
                float m4 = fmaxf(fmaxf(rmax[rs][0], rmax[rs][1]),
                                 fmaxf(rmax[rs][2], rmax[rs][3]));
                qscale[grow] = (m4 > 0.f) ? m4 / 255.f : 0.f;
            }
        }
    }
#undef PHASE
#undef TILE_MFMA
#undef LOADB
}

// ---------------------------------------------------------------------------
// c_b[i] = (sum_j f_bonds[a2b[i][j]][133:147]) @ W_h[512:526] -> bf16
// ---------------------------------------------------------------------------
__global__ __launch_bounds__(256) void cb_k(const float* __restrict__ f_bonds,
                                            const int*   __restrict__ a2b,
                                            const float* __restrict__ Wh2,
                                            unsigned short* __restrict__ cb, int M)
{
    int atom = blockIdx.x * 4 + (threadIdx.x >> 6);
    int lane = threadIdx.x & 63;
    if (atom >= M) return;
    int bidx = (lane < MAX_NB) ? a2b[(size_t)atom * MAX_NB + lane] : 0;
    float nb = 0.f;
    if (lane < BOND_FDIM) {
        #pragma unroll
        for (int j = 0; j < MAX_NB; j++) {
            int b = __shfl(bidx, j);
            nb += f_bonds[(size_t)b * FB_DIM + ATOM_FDIM + lane];
        }
    }
    float acc[8];
    #pragma unroll
    for (int ci = 0; ci < 8; ci++) acc[ci] = 0.f;
    #pragma unroll
    for (int k = 0; k < BOND_FDIM; k++) {
        float nbk = __shfl(nb, k);
        #pragma unroll
        for (int ci = 0; ci < 8; ci++)
            acc[ci] += nbk * Wh2[(size_t)k * HIDDEN + lane + (ci << 6)];
    }
    size_t rb = (size_t)atom * HIDDEN;
    #pragma unroll
    for (int ci = 0; ci < 8; ci++) cb[rb + lane + (ci << 6)] = fb(acc[ci]);
}

// ---------------------------------------------------------------------------
// Per-molecule segment mean + counts (+ fused nz from atomf row-sums).
// ---------------------------------------------------------------------------
__global__ __launch_bounds__(512) void seg_k(const unsigned short* __restrict__ hid,
                                             const float* __restrict__ atomf,
                                             const int*   __restrict__ mol_ids,
                                             float* __restrict__ out, int M, int NM)
{
    int m = blockIdx.x;
    int t = threadIdx.x;
    int lo = 0, hi = M;
    while (lo < hi) { int mid = (lo + hi) >> 1; if (mol_ids[mid] < m) lo = mid + 1; else hi = mid; }
    int s = lo;
    lo = 0; hi = M;
    while (lo < hi) { int mid = (lo + hi) >> 1; if (mol_ids[mid] < m + 1) lo = mid + 1; else hi = mid; }
    int e = lo;

    float acc = 0.f;
    for (int a = s; a < e; a++) acc += uf(hid[(size_t)a * HIDDEN + t]);

    float nzp = 0.f;
    for (int a = s + t; a < e; a += 512) {
        const float* r = atomf + (size_t)a * ATOM_FDIM;
        float ss = 0.f;
        #pragma unroll 7
        for (int c = 0; c < ATOM_FDIM; c++) ss += r[c];
        nzp += (ss > 0.f) ? 1.f : 0.f;
    }
    __shared__ float red[512];
    red[t] = nzp; __syncthreads();
    for (int off = 256; off; off >>= 1) { if (t < off) red[t] += red[t + off]; __syncthreads(); }

    int cnt = e - s;
    float inv = 1.f / fmaxf((float)cnt, 1.f);
    out[(size_t)m * HIDDEN + t] = acc * inv;
    if (t == 0) {
        out[(size_t)NM * HIDDEN + 2 * m]     = red[0];
        out[(size_t)NM * HIDDEN + 2 * m + 1] = (float)cnt;
    }
}

// ---------------------------------------------------------------------------
extern "C" void kernel_launch(void* const* d_in, const int* in_sizes, int n_in,
                              void* d_out, int out_size, void* d_ws, size_t ws_size,
                              hipStream_t stream)
{
    const float* atomf   = (const float*)d_in[0];
    const float* f_bonds = (const float*)d_in[1];
    const int*   a2a     = (const int*)d_in[2];
    const int*   a2b     = (const int*)d_in[3];
    const int*   mol_ids = (const int*)d_in[4];
    const float* W_i     = (const float*)d_in[5];
    const float* W_h     = (const float*)d_in[6];
    const float* W_o     = (const float*)d_in[7];
    const float* b_o     = (const float*)d_in[8];
    float* out = (float*)d_out;

    const int M  = in_sizes[2] / MAX_NB;   // 100000
    const int NM = 1000;
    const size_t SZ = (size_t)M * HIDDEN;

    const float* Wh2f = W_h + (size_t)HIDDEN * HIDDEN;

    // ---- workspace layout ----
    const size_t TCH = HIDDEN * 32;                 // ushorts per tile
    unsigned short* WiT  = (unsigned short*)d_ws;
    unsigned short* Wh1T = WiT  + 5  * TCH;
    unsigned short* Wo1T = Wh1T + 16 * TCH;
    unsigned short* Wo2T = Wo1T + 5  * TCH;
    char* p = (char*)(Wo2T + 16 * TCH);             // 42 tiles = 1.38 MB
    unsigned short* baseB = (unsigned short*)p; p += SZ * 2;   // bf16 base / hid
    unsigned char*  msgQA = (unsigned char*)p;  p += SZ;       // u8 messages
    unsigned char*  msgQB = (unsigned char*)p;  p += SZ;
    float* scaleA = (float*)p; p += (size_t)M * 4;
    float* scaleB = (float*)p;

    const int gA = (M + 3) / 4;
    const int gG = (M + BM - 1) / BM;               // 3125

    // ---- weight conversion (fragment-ordered bf16 tiles) ----
    cvt_w<<<(5  * 2048 + 255) / 256, 256, 0, stream>>>(W_i,  WiT,  ATOM_FDIM, 5  * 2048);
    cvt_w<<<(16 * 2048 + 255) / 256, 256, 0, stream>>>(W_h,  Wh1T, HIDDEN,    16 * 2048);
    cvt_w<<<(5  * 2048 + 255) / 256, 256, 0, stream>>>(W_o,  Wo1T, ATOM_FDIM, 5  * 2048);
    cvt_w<<<(16 * 2048 + 255) / 256, 256, 0, stream>>>(W_o + (size_t)ATOM_FDIM * HIDDEN,
                                                       Wo2T, HIDDEN, 16 * 2048);

    // c_b (bond@Wh2) -> baseB
    cb_k<<<gA, 256, 0, stream>>>(f_bonds, a2b, Wh2f, baseB, M);
    // EPI0: acc = atomf@Wi; baseB += acc; msgQA = quant(relu(acc))
    mfma_gemm<0, false, true><<<gG, 512, 0, stream>>>(
        nullptr, nullptr, nullptr, nullptr, atomf, WiT,
        nullptr, nullptr, nullptr, baseB, msgQA, scaleA, M);
    // 3 iters: msg' = quant(relu(g6(msg)@Wh1 + base))
    mfma_gemm<1, true, false><<<gG, 512, 0, stream>>>(
        msgQA, scaleA, a2a, Wh1T, nullptr, nullptr,
        baseB, nullptr, nullptr, nullptr, msgQB, scaleB, M);
    mfma_gemm<1, true, false><<<gG, 512, 0, stream>>>(
        msgQB, scaleB, a2a, Wh1T, nullptr, nullptr,
        baseB, nullptr, nullptr, nullptr, msgQA, scaleA, M);
    mfma_gemm<1, true, false><<<gG, 512, 0, stream>>>(
        msgQA, scaleA, a2a, Wh1T, nullptr, nullptr,
        baseB, nullptr, nullptr, nullptr, msgQB, scaleB, M);
    // hid = relu(g6(msgQB)@Wo2 + atomf@Wo1 + b_o) -> baseB (bf16, reuse)
    mfma_gemm<2, true, true><<<gG, 512, 0, stream>>>(
        msgQB, scaleB, a2a, Wo2T, atomf, Wo1T,
        nullptr, b_o, baseB, nullptr, nullptr, nullptr, M);
    // segment mean + counts (+ fused nz)
    seg_k<<<NM, 512, 0, stream>>>(baseB, atomf, mol_ids, out, M, NM);
}

// Round 10
// 1278.728 us; speedup vs baseline: 1.1189x; 1.1189x over previous
//
#include <hip/hip_runtime.h>
#include <hip/hip_bf16.h>
#include <cstddef>

#define HIDDEN 512
#define ATOM_FDIM 133
#define BOND_FDIM 14
#define FB_DIM 147
#define MAX_NB 6
#define BM 64

typedef __attribute__((ext_vector_type(8)))  short         s16x8;
typedef __attribute__((ext_vector_type(16))) unsigned char u8x16;
typedef __attribute__((ext_vector_type(8)))  unsigned char u8x8;
typedef __attribute__((ext_vector_type(8)))  signed char   s8x8;
typedef __attribute__((ext_vector_type(4)))  float         f32x4;

__device__ __forceinline__ float uf(unsigned short u) {
    return __uint_as_float(((unsigned)u) << 16);
}
__device__ __forceinline__ unsigned short fb(float f) {
    __hip_bfloat16 h = __float2bfloat16(f);
    return *reinterpret_cast<unsigned short*>(&h);
}

// LDS A tile: 64 chunks(16B = 8 bf16 k-octet) x 64 rows, XOR-swizzled.
#define A_UNIT(ch, row) (((ch) << 6) + ((row) ^ ((ch) & 7)))

// ---------------------------------------------------------------------------
// One-time weight convert: f32 [Ksrc][512] -> bf16 MFMA-fragment order.
// ---------------------------------------------------------------------------
__global__ __launch_bounds__(256) void cvt_w(const float* __restrict__ src,
                                             unsigned short* __restrict__ dst,
                                             int Ksrc, int nchunks)
{
    int c = blockIdx.x * 256 + threadIdx.x;
    if (c >= nchunks) return;
    int tile = c >> 11, pc = c & 2047, n = pc >> 2, s = pc & 3;
    s16x8 o;
    #pragma unroll
    for (int e = 0; e < 8; e++) {
        int k = tile * 32 + s * 8 + e;
        float v = (k < Ksrc) ? src[(size_t)k * HIDDEN + n] : 0.f;
        o[e] = (short)fb(v);
    }
    reinterpret_cast<s16x8*>(dst)[c] = o;
}

// ---------------------------------------------------------------------------
// DENSE MFMA GEMM, 512 thr = 8 waves (2M x 4N), BM=64 x BN=512.
// A is read LINEARLY (no gather): AU8 -> u8 msg + per-row scale (K=512);
// else f32 atomf (K=160 pad of 133).  B = L2-hot fragment-ordered bf16.
// EPI 0: baseOut += acc (bf16 RMW); u8-quant(relu(acc)) -> qout/qscale.
// EPI 1: i8 rowwise quant of raw acc -> qout/qscale.     (Y = msg @ W)
// EPI 2: outv = bf16 (acc + bias)   (no relu; fo buffer)
// ---------------------------------------------------------------------------
template<int EPI, bool AU8>
__global__ __launch_bounds__(512, 4) void dgemm(
    const unsigned char* __restrict__ Aq, const float* __restrict__ Ascale,
    const float* __restrict__ Af32,
    const unsigned short* __restrict__ Wt,
    const float* __restrict__ bias,
    unsigned short* __restrict__ outv,
    unsigned short* __restrict__ baseOut,
    unsigned char* __restrict__ qout, float* __restrict__ qscale,
    int M)
{
    constexpr int NT = AU8 ? 16 : 5;
    __shared__ s16x8 As[64 * BM];                    // 64 KB
    __shared__ float rmax[BM][4];

    const int t    = threadIdx.x;
    const int m0   = blockIdx.x * BM;
    const int lane = t & 63;
    const int l15  = lane & 15, lhi = lane >> 4;
    const int w    = t >> 6, wm = w >> 2, wn = w & 3;
    const int rs   = t >> 3, oc = t & 7;             // staging: row, 64B-slot

    int srow = m0 + rs; if (srow >= M) srow = M - 1;

    f32x4 acc[2][8];
    #pragma unroll
    for (int mr = 0; mr < 2; mr++)
        #pragma unroll
        for (int nr = 0; nr < 8; nr++)
            acc[mr][nr] = (f32x4){0.f, 0.f, 0.f, 0.f};

#define LOADB(B_, TILE) do {                                                  \
    const s16x8* bb_ = reinterpret_cast<const s16x8*>(                        \
        Wt + (size_t)(TILE) * (HIDDEN * 32)) + ((wn * 128 + l15) * 4 + lhi);  \
    _Pragma("unroll")                                                         \
    for (int nr_ = 0; nr_ < 8; nr_++) B_[nr_] = bb_[nr_ * 64];                \
} while (0)

#define TILE_MFMA(TILE, B_) do {                                              \
    s16x8 a0_ = As[A_UNIT((TILE) * 4 + lhi, wm * 32 + l15)];                  \
    s16x8 a1_ = As[A_UNIT((TILE) * 4 + lhi, wm * 32 + 16 + l15)];             \
    _Pragma("unroll")                                                         \
    for (int nr_ = 0; nr_ < 8; nr_++) {                                       \
        acc[0][nr_] = __builtin_amdgcn_mfma_f32_16x16x32_bf16(a0_, B_[nr_], acc[0][nr_], 0, 0, 0); \
        acc[1][nr_] = __builtin_amdgcn_mfma_f32_16x16x32_bf16(a1_, B_[nr_], acc[1][nr_], 0, 0, 0); \
    }                                                                         \
} while (0)

    // ---- A staging (linear, coalesced) ----
    if (AU8) {
        float sc = Ascale[srow];
        const u8x16* src = reinterpret_cast<const u8x16*>(
            Aq + (size_t)srow * HIDDEN + oc * 64);
        u8x16 v[4];
        #pragma unroll
        for (int i = 0; i < 4; i++) v[i] = src[i];
        #pragma unroll
        for (int i = 0; i < 4; i++) {
            s16x8 o0, o1;
            #pragma unroll
            for (int e = 0; e < 8; e++) {
                o0[e] = (short)fb(sc * (float)v[i][e]);
                o1[e] = (short)fb(sc * (float)v[i][e + 8]);
            }
            int ch = oc * 8 + i * 2;
            As[A_UNIT(ch, rs)]     = o0;
            As[A_UNIT(ch + 1, rs)] = o1;
        }
    } else {
        int grow = m0 + rs;
        bool ok = grow < M;
        #pragma unroll
        for (int c8 = 0; c8 < 3; ++c8) {
            int ch = c8 * 8 + oc;
            if (ch >= 20) break;
            s16x8 o;
            #pragma unroll
            for (int e = 0; e < 8; e++) {
                int k = ch * 8 + e;
                float v = (ok && k < ATOM_FDIM)
                              ? Af32[(size_t)grow * ATOM_FDIM + k] : 0.f;
                o[e] = (short)fb(v);
            }
            As[A_UNIT(ch, rs)] = o;
        }
    }
    __syncthreads();

    {
        s16x8 b_[8];
        #pragma unroll 2
        for (int tp = 0; tp < NT; ++tp) {
            LOADB(b_, tp);
            TILE_MFMA(tp, b_);
        }
    }

    // ======================= epilogues =======================
    if (EPI == 2) {
        #pragma unroll
        for (int mr = 0; mr < 2; mr++)
            #pragma unroll
            for (int nr = 0; nr < 8; nr++) {
                int col = wn * 128 + nr * 16 + l15;
                #pragma unroll
                for (int rg = 0; rg < 4; rg++) {
                    int row = m0 + wm * 32 + mr * 16 + lhi * 4 + rg;
                    if (row >= M) continue;
                    outv[(size_t)row * HIDDEN + col] =
                        fb(acc[mr][nr][rg] + bias[col]);
                }
            }
        return;
    }

    if (EPI == 0) {   // baseOut += acc; acc = relu(acc)
        #pragma unroll
        for (int mr = 0; mr < 2; mr++)
            #pragma unroll
            for (int nr = 0; nr < 8; nr++) {
                int col = wn * 128 + nr * 16 + l15;
                #pragma unroll
                for (int rg = 0; rg < 4; rg++) {
                    int row = m0 + wm * 32 + mr * 16 + lhi * 4 + rg;
                    if (row < M) {
                        size_t idx = (size_t)row * HIDDEN + col;
                        baseOut[idx] = fb(acc[mr][nr][rg] + uf(baseOut[idx]));
                    }
                    acc[mr][nr][rg] = fmaxf(acc[mr][nr][rg], 0.f);
                }
            }
    }

    // per-row (abs)max: 8 cols/lane -> 128/wave -> LDS across 4 wn-waves
    #pragma unroll
    for (int mr = 0; mr < 2; mr++)
        #pragma unroll
        for (int rg = 0; rg < 4; rg++) {
            float pm = 0.f;
            #pragma unroll
            for (int nr = 0; nr < 8; nr++) {
                float v = acc[mr][nr][rg];
                pm = fmaxf(pm, (EPI == 1) ? fabsf(v) : v);
            }
            pm = fmaxf(pm, __shfl_xor(pm, 1));
            pm = fmaxf(pm, __shfl_xor(pm, 2));
            pm = fmaxf(pm, __shfl_xor(pm, 4));
            pm = fmaxf(pm, __shfl_xor(pm, 8));
            if (l15 == 0) rmax[wm * 32 + mr * 16 + lhi * 4 + rg][wn] = pm;
        }
    __syncthreads();   // also: all MFMA reads of As done -> reuse As below

    char* qb = reinterpret_cast<char*>(As);
    #pragma unroll
    for (int mr = 0; mr < 2; mr++)
        #pragma unroll
        for (int rg = 0; rg < 4; rg++) {
            int lrow = wm * 32 + mr * 16 + lhi * 4 + rg;
            float m4 = fmaxf(fmaxf(rmax[lrow][0], rmax[lrow][1]),
                             fmaxf(rmax[lrow][2], rmax[lrow][3]));
            float inv = (m4 > 0.f) ? ((EPI == 1) ? 127.f : 255.f) / m4 : 0.f;
            #pragma unroll
            for (int nr = 0; nr < 8; nr++) {
                int col = wn * 128 + nr * 16 + l15;
                float v = acc[mr][nr][rg] * inv;
                if (EPI == 1) {
                    int q = (int)rintf(v);
                    q = (q > 127) ? 127 : ((q < -127) ? -127 : q);
                    qb[lrow * HIDDEN + col] = (char)q;
                } else {
                    qb[lrow * HIDDEN + col] = (char)(unsigned char)(v + 0.5f);
                }
            }
        }
    __syncthreads();

    {
        int grow = m0 + rs;
        if (grow < M) {
            #pragma unroll
            for (int i = 0; i < 4; i++) {
                u8x16 vq = *reinterpret_cast<const u8x16*>(
                    &qb[rs * HIDDEN + oc * 64 + i * 16]);
                *reinterpret_cast<u8x16*>(
                    &qout[(size_t)grow * HIDDEN + oc * 64 + i * 16]) = vq;
            }
            if (oc == 0) {
                float m4 = fmaxf(fmaxf(rmax[rs][0], rmax[rs][1]),
                                 fmaxf(rmax[rs][2], rmax[rs][3]));
                qscale[grow] = (m4 > 0.f)
                    ? m4 / ((EPI == 1) ? 127.f : 255.f) : 0.f;
            }
        }
    }
#undef TILE_MFMA
#undef LOADB
}

// ---------------------------------------------------------------------------
// Post-GEMM gather: out[i] = relu(base[i] + sum_j ysc[a2a_j] * Yq[a2a_j]).
// One wave per atom, full occupancy, pure loads (no LDS, no MFMA regs).
// !FINAL: u8-quantize -> qout/qscale.  FINAL: bf16 -> outb (in-place on base).
// ---------------------------------------------------------------------------
template<bool FINAL>
__global__ __launch_bounds__(256) void gath_k(
    const signed char* __restrict__ Yq, const float* __restrict__ ysc,
    const int* __restrict__ a2a,
    const unsigned short* __restrict__ base,
    unsigned char* __restrict__ qout, float* __restrict__ qscale,
    unsigned short* __restrict__ outb,
    int M)
{
    int a    = (blockIdx.x * 256 + threadIdx.x) >> 6;
    int lane = threadIdx.x & 63;
    if (a >= M) return;

    float s[8] = {0.f, 0.f, 0.f, 0.f, 0.f, 0.f, 0.f, 0.f};
    #pragma unroll
    for (int j = 0; j < MAX_NB; j++) {
        int n    = a2a[(size_t)a * MAX_NB + j];
        float sc = ysc[n];
        s8x8 v = *reinterpret_cast<const s8x8*>(Yq + (size_t)n * HIDDEN + lane * 8);
        #pragma unroll
        for (int e = 0; e < 8; e++) s[e] += sc * (float)v[e];
    }
    s16x8 b = *reinterpret_cast<const s16x8*>(base + (size_t)a * HIDDEN + lane * 8);
    #pragma unroll
    for (int e = 0; e < 8; e++)
        s[e] = fmaxf(s[e] + uf((unsigned short)b[e]), 0.f);

    if (FINAL) {
        s16x8 o;
        #pragma unroll
        for (int e = 0; e < 8; e++) o[e] = (short)fb(s[e]);
        *reinterpret_cast<s16x8*>(outb + (size_t)a * HIDDEN + lane * 8) = o;
    } else {
        float mx = s[0];
        #pragma unroll
        for (int e = 1; e < 8; e++) mx = fmaxf(mx, s[e]);
        #pragma unroll
        for (int off = 1; off < 64; off <<= 1)
            mx = fmaxf(mx, __shfl_xor(mx, off));
        float inv = (mx > 0.f) ? 255.f / mx : 0.f;
        u8x8 q;
        #pragma unroll
        for (int e = 0; e < 8; e++) q[e] = (unsigned char)(s[e] * inv + 0.5f);
        *reinterpret_cast<u8x8*>(qout + (size_t)a * HIDDEN + lane * 8) = q;
        if (lane == 0) qscale[a] = (mx > 0.f) ? mx / 255.f : 0.f;
    }
}

// ---------------------------------------------------------------------------
// c_b[i] = (sum_j f_bonds[a2b[i][j]][133:147]) @ W_h[512:526] -> bf16
// ---------------------------------------------------------------------------
__global__ __launch_bounds__(256) void cb_k(const float* __restrict__ f_bonds,
                                            const int*   __restrict__ a2b,
                                            const float* __restrict__ Wh2,
                                            unsigned short* __restrict__ cb, int M)
{
    int atom = blockIdx.x * 4 + (threadIdx.x >> 6);
    int lane = threadIdx.x & 63;
    if (atom >= M) return;
    int bidx = (lane < MAX_NB) ? a2b[(size_t)atom * MAX_NB + lane] : 0;
    float nb = 0.f;
    if (lane < BOND_FDIM) {
        #pragma unroll
        for (int j = 0; j < MAX_NB; j++) {
            int b = __shfl(bidx, j);
            nb += f_bonds[(size_t)b * FB_DIM + ATOM_FDIM + lane];
        }
    }
    float acc[8];
    #pragma unroll
    for (int ci = 0; ci < 8; ci++) acc[ci] = 0.f;
    #pragma unroll
    for (int k = 0; k < BOND_FDIM; k++) {
        float nbk = __shfl(nb, k);
        #pragma unroll
        for (int ci = 0; ci < 8; ci++)
            acc[ci] += nbk * Wh2[(size_t)k * HIDDEN + lane + (ci << 6)];
    }
    size_t rb = (size_t)atom * HIDDEN;
    #pragma unroll
    for (int ci = 0; ci < 8; ci++) cb[rb + lane + (ci << 6)] = fb(acc[ci]);
}

// ---------------------------------------------------------------------------
// Per-molecule segment mean + counts (+ fused nz from atomf row-sums).
// ---------------------------------------------------------------------------
__global__ __launch_bounds__(512) void seg_k(const unsigned short* __restrict__ hid,
                                             const float* __restrict__ atomf,
                                             const int*   __restrict__ mol_ids,
                                             float* __restrict__ out, int M, int NM)
{
    int m = blockIdx.x;
    int t = threadIdx.x;
    int lo = 0, hi = M;
    while (lo < hi) { int mid = (lo + hi) >> 1; if (mol_ids[mid] < m) lo = mid + 1; else hi = mid; }
    int s = lo;
    lo = 0; hi = M;
    while (lo < hi) { int mid = (lo + hi) >> 1; if (mol_ids[mid] < m + 1) lo = mid + 1; else hi = mid; }
    int e = lo;

    float acc = 0.f;
    for (int a = s; a < e; a++) acc += uf(hid[(size_t)a * HIDDEN + t]);

    float nzp = 0.f;
    for (int a = s + t; a < e; a += 512) {
        const float* r = atomf + (size_t)a * ATOM_FDIM;
        float ss = 0.f;
        #pragma unroll 7
        for (int c = 0; c < ATOM_FDIM; c++) ss += r[c];
        nzp += (ss > 0.f) ? 1.f : 0.f;
    }
    __shared__ float red[512];
    red[t] = nzp; __syncthreads();
    for (int off = 256; off; off >>= 1) { if (t < off) red[t] += red[t + off]; __syncthreads(); }

    int cnt = e - s;
    float inv = 1.f / fmaxf((float)cnt, 1.f);
    out[(size_t)m * HIDDEN + t] = acc * inv;
    if (t == 0) {
        out[(size_t)NM * HIDDEN + 2 * m]     = red[0];
        out[(size_t)NM * HIDDEN + 2 * m + 1] = (float)cnt;
    }
}

// ---------------------------------------------------------------------------
extern "C" void kernel_launch(void* const* d_in, const int* in_sizes, int n_in,
                              void* d_out, int out_size, void* d_ws, size_t ws_size,
                              hipStream_t stream)
{
    const float* atomf   = (const float*)d_in[0];
    const float* f_bonds = (const float*)d_in[1];
    const int*   a2a     = (const int*)d_in[2];
    const int*   a2b     = (const int*)d_in[3];
    const int*   mol_ids = (const int*)d_in[4];
    const float* W_i     = (const float*)d_in[5];
    const float* W_h     = (const float*)d_in[6];
    const float* W_o     = (const float*)d_in[7];
    const float* b_o     = (const float*)d_in[8];
    float* out = (float*)d_out;

    const int M  = in_sizes[2] / MAX_NB;   // 100000
    const int NM = 1000;
    const size_t SZ = (size_t)M * HIDDEN;

    const float* Wh2f = W_h + (size_t)HIDDEN * HIDDEN;

    // ---- workspace layout ----
    const size_t TCH = HIDDEN * 32;                 // ushorts per tile
    unsigned short* WiT  = (unsigned short*)d_ws;
    unsigned short* Wh1T = WiT  + 5  * TCH;
    unsigned short* Wo1T = Wh1T + 16 * TCH;
    unsigned short* Wo2T = Wo1T + 5  * TCH;
    char* p = (char*)(Wo2T + 16 * TCH);             // 42 tiles = 1.38 MB
    unsigned short* baseB = (unsigned short*)p; p += SZ * 2;  // bf16 base
    unsigned short* foB   = (unsigned short*)p; p += SZ * 2;  // bf16 fo / hid
    unsigned char*  msgQ  = (unsigned char*)p;  p += SZ;      // u8 messages
    signed char*    Yq    = (signed char*)p;    p += SZ;      // i8 Y
    float* scaleM = (float*)p; p += (size_t)M * 4;
    float* scaleY = (float*)p;

    const int gA = (M + 3) / 4;                     // 1 wave / atom kernels
    const int gG = (M + BM - 1) / BM;               // 1563

    // ---- weight conversion (fragment-ordered bf16 tiles) ----
    cvt_w<<<(5  * 2048 + 255) / 256, 256, 0, stream>>>(W_i,  WiT,  ATOM_FDIM, 5  * 2048);
    cvt_w<<<(16 * 2048 + 255) / 256, 256, 0, stream>>>(W_h,  Wh1T, HIDDEN,    16 * 2048);
    cvt_w<<<(5  * 2048 + 255) / 256, 256, 0, stream>>>(W_o,  Wo1T, ATOM_FDIM, 5  * 2048);
    cvt_w<<<(16 * 2048 + 255) / 256, 256, 0, stream>>>(W_o + (size_t)ATOM_FDIM * HIDDEN,
                                                       Wo2T, HIDDEN, 16 * 2048);

    // c_b (bond@Wh2) -> baseB
    cb_k<<<gA, 256, 0, stream>>>(f_bonds, a2b, Wh2f, baseB, M);
    // G0a: acc = atomf@Wi; baseB += acc; msgQ = u8quant(relu(acc))
    dgemm<0, false><<<gG, 512, 0, stream>>>(
        nullptr, nullptr, atomf, WiT, nullptr,
        nullptr, baseB, msgQ, scaleM, M);
    // G0b: foB = atomf@Wo1 + b_o (pre-relu)
    dgemm<2, false><<<gG, 512, 0, stream>>>(
        nullptr, nullptr, atomf, Wo1T, b_o,
        foB, nullptr, nullptr, nullptr, M);
    // 3 iters: Y = msg@Wh1 (dense) ; msg' = u8quant(relu(base + gather6(Y)))
    for (int it = 0; it < 3; ++it) {
        dgemm<1, true><<<gG, 512, 0, stream>>>(
            msgQ, scaleM, nullptr, Wh1T, nullptr,
            nullptr, nullptr, (unsigned char*)Yq, scaleY, M);
        gath_k<false><<<gA, 256, 0, stream>>>(
            Yq, scaleY, a2a, baseB, msgQ, scaleM, nullptr, M);
    }
    // Yo = msg3@Wo2 (dense) ; hid = relu(foB + gather6(Yo)) in place
    dgemm<1, true><<<gG, 512, 0, stream>>>(
        msgQ, scaleM, nullptr, Wo2T, nullptr,
        nullptr, nullptr, (unsigned char*)Yq, scaleY, M);
    gath_k<true><<<gA, 256, 0, stream>>>(
        Yq, scaleY, a2a, foB, nullptr, nullptr, foB, M);
    // segment mean + counts (+ fused nz)
    seg_k<<<NM, 512, 0, stream>>>(foB, atomf, mol_ids, out, M, NM);
}